// Round 1
// baseline (51.553 us; speedup 1.0000x reference)
//
#include <hip/hip_runtime.h>

constexpr int IN_DIM = 21;
constexpr int HID = 5;
constexpr int GATES = 4 * HID;   // 20
constexpr int BLK = 256;

__device__ __forceinline__ float fast_sigmoid(float x) {
    // 1 / (1 + e^-x); saturates correctly: x->+inf => 1, x->-inf => 0
    return __fdividef(1.0f, 1.0f + __expf(-x));
}

__device__ __forceinline__ float fast_tanh(float x) {
    // 1 - 2/(e^{2x}+1); x->+inf => 1 (e->inf, div->0), x->-inf => -1 (e->0)
    return 1.0f - __fdividef(2.0f, __expf(2.0f * x) + 1.0f);
}

__global__ __launch_bounds__(BLK) void lstm2_head_kernel(
    const float* __restrict__ x,
    const float* __restrict__ h0,
    const float* __restrict__ c0,
    const float* __restrict__ Wih0,
    const float* __restrict__ Whh0,
    const float* __restrict__ bih0,
    const float* __restrict__ bhh0,
    const float* __restrict__ Wih1,
    const float* __restrict__ Whh1,
    const float* __restrict__ bih1,
    const float* __restrict__ bhh1,
    const float* __restrict__ Wlin,
    const float* __restrict__ blin,
    float* __restrict__ out,
    int B)
{
    __shared__ float xs[BLK * IN_DIM];  // 21.5 KB

    const size_t b0 = (size_t)blockIdx.x * BLK;
    const int nrow = (int)((B - (int)b0) < BLK ? (B - (int)b0) : BLK);

    // Coalesced stage of the contiguous x tile [b0..b0+nrow) x IN_DIM
    {
        const float* xsrc = x + b0 * IN_DIM;
        const int tot = nrow * IN_DIM;
        for (int i = threadIdx.x; i < tot; i += BLK) xs[i] = xsrc[i];
    }
    __syncthreads();

    const int t = threadIdx.x;
    if (t >= nrow) return;
    const int e = (int)b0 + t;

    // LDS -> regs: stride 21 words, 21 coprime 32 => <=2-way bank aliasing (free)
    float xi[IN_DIM];
#pragma unroll
    for (int j = 0; j < IN_DIM; ++j) xi[j] = xs[t * IN_DIM + j];

    // ---------------- layer 0 ----------------
    float hp[HID], cp[HID];
#pragma unroll
    for (int k = 0; k < HID; ++k) {
        hp[k] = h0[(size_t)e * HID + k];
        cp[k] = c0[(size_t)e * HID + k];
    }

    float g[GATES];
#pragma unroll
    for (int r = 0; r < GATES; ++r) {
        float acc = bih0[r] + bhh0[r];           // uniform: s_load
#pragma unroll
        for (int j = 0; j < IN_DIM; ++j)
            acc = fmaf(Wih0[r * IN_DIM + j], xi[j], acc);
#pragma unroll
        for (int k = 0; k < HID; ++k)
            acc = fmaf(Whh0[r * HID + k], hp[k], acc);
        g[r] = acc;
    }

    float h1[HID];
#pragma unroll
    for (int k = 0; k < HID; ++k) {
        float ig = fast_sigmoid(g[k]);
        float fg = fast_sigmoid(g[HID + k]);
        float gg = fast_tanh(g[2 * HID + k]);
        float og = fast_sigmoid(g[3 * HID + k]);
        float cn = fmaf(fg, cp[k], ig * gg);
        h1[k] = og * fast_tanh(cn);
    }

    // ---------------- layer 1 ----------------
    const size_t off1 = (size_t)B * HID;  // h0[1], c0[1]
#pragma unroll
    for (int k = 0; k < HID; ++k) {
        hp[k] = h0[off1 + (size_t)e * HID + k];
        cp[k] = c0[off1 + (size_t)e * HID + k];
    }

#pragma unroll
    for (int r = 0; r < GATES; ++r) {
        float acc = bih1[r] + bhh1[r];
#pragma unroll
        for (int j = 0; j < HID; ++j)
            acc = fmaf(Wih1[r * HID + j], h1[j], acc);
#pragma unroll
        for (int k = 0; k < HID; ++k)
            acc = fmaf(Whh1[r * HID + k], hp[k], acc);
        g[r] = acc;
    }

    float h2[HID];
#pragma unroll
    for (int k = 0; k < HID; ++k) {
        float ig = fast_sigmoid(g[k]);
        float fg = fast_sigmoid(g[HID + k]);
        float gg = fast_tanh(g[2 * HID + k]);
        float og = fast_sigmoid(g[3 * HID + k]);
        float cn = fmaf(fg, cp[k], ig * gg);
        h2[k] = og * fast_tanh(cn);
    }

    // ---------------- linear head + tanh ----------------
    float o = blin[0];
#pragma unroll
    for (int k = 0; k < HID; ++k) o = fmaf(Wlin[k], h2[k], o);
    out[e] = fast_tanh(o);
}

extern "C" void kernel_launch(void* const* d_in, const int* in_sizes, int n_in,
                              void* d_out, int out_size, void* d_ws, size_t ws_size,
                              hipStream_t stream) {
    const float* x    = (const float*)d_in[0];
    const float* h0   = (const float*)d_in[1];
    const float* c0   = (const float*)d_in[2];
    const float* Wih0 = (const float*)d_in[3];
    const float* Whh0 = (const float*)d_in[4];
    const float* bih0 = (const float*)d_in[5];
    const float* bhh0 = (const float*)d_in[6];
    const float* Wih1 = (const float*)d_in[7];
    const float* Whh1 = (const float*)d_in[8];
    const float* bih1 = (const float*)d_in[9];
    const float* bhh1 = (const float*)d_in[10];
    const float* Wlin = (const float*)d_in[11];
    const float* blin = (const float*)d_in[12];
    float* out = (float*)d_out;

    const int B = in_sizes[0] / IN_DIM;
    const int grid = (B + BLK - 1) / BLK;
    lstm2_head_kernel<<<grid, BLK, 0, stream>>>(
        x, h0, c0, Wih0, Whh0, bih0, bhh0, Wih1, Whh1, bih1, bhh1,
        Wlin, blin, out, B);
}

// Round 2
// 41.044 us; speedup vs baseline: 1.2561x; 1.2561x over previous
//
#include <hip/hip_runtime.h>

typedef float v2f __attribute__((ext_vector_type(2)));

constexpr int IN_DIM = 21;
constexpr int HID = 5;
constexpr int BLK = 256;
constexpr float LOG2E = 1.44269504088896340736f;

__device__ __forceinline__ v2f splat(float s) { v2f r; r.x = s; r.y = s; return r; }
__device__ __forceinline__ v2f vfma(v2f a, v2f b, v2f c) {
    return __builtin_elementwise_fma(a, b, c);
}
__device__ __forceinline__ v2f vexp2(v2f x) {
    v2f r; r.x = __builtin_amdgcn_exp2f(x.x); r.y = __builtin_amdgcn_exp2f(x.y); return r;
}
__device__ __forceinline__ v2f vrcp(v2f x) {
    v2f r; r.x = __builtin_amdgcn_rcpf(x.x); r.y = __builtin_amdgcn_rcpf(x.y); return r;
}
// sigmoid(x) = 1/(1+exp(-x)); saturates correctly at +/-inf
__device__ __forceinline__ v2f sigmoid2(v2f x) {
    v2f t = vexp2(x * splat(-LOG2E));     // exp(-x)
    return vrcp(t + splat(1.0f));
}
// tanh(x) = 1 - 2/(exp(2x)+1); saturates correctly at +/-inf
__device__ __forceinline__ v2f tanh2(v2f x) {
    v2f t = vexp2(x * splat(2.0f * LOG2E));  // exp(2x)
    v2f r = vrcp(t + splat(1.0f));
    return vfma(splat(-2.0f), r, splat(1.0f));
}

__global__ __launch_bounds__(BLK) void lstm2_head_pk(
    const float* __restrict__ x,
    const float* __restrict__ h0,
    const float* __restrict__ c0,
    const float* __restrict__ Wih0,
    const float* __restrict__ Whh0,
    const float* __restrict__ bih0,
    const float* __restrict__ bhh0,
    const float* __restrict__ Wih1,
    const float* __restrict__ Whh1,
    const float* __restrict__ bih1,
    const float* __restrict__ bhh1,
    const float* __restrict__ Wlin,
    const float* __restrict__ blin,
    float* __restrict__ out,
    int B)
{
    const long long e0 = 2LL * ((long long)blockIdx.x * BLK + threadIdx.x);
    if (e0 >= B) return;
    const int eb = (e0 + 1 < B) ? 1 : 0;   // second element valid?

    // ---- load x for both elements, interleaved into v2f lanes ----
    const float* xa = x + e0 * IN_DIM;
    v2f xv[IN_DIM];
#pragma unroll
    for (int j = 0; j < IN_DIM; ++j) {
        xv[j].x = xa[j];
        xv[j].y = xa[j + IN_DIM * eb];
    }

    // ---- layer 0 state ----
    const float* h0p = h0 + e0 * HID;
    const float* c0p = c0 + e0 * HID;
    v2f hv[HID], cv[HID];
#pragma unroll
    for (int k = 0; k < HID; ++k) {
        hv[k].x = h0p[k];          hv[k].y = h0p[k + HID * eb];
        cv[k].x = c0p[k];          cv[k].y = c0p[k + HID * eb];
    }

    // ---- layer 0: per-k gate quadruple, immediate activation ----
    v2f h1[HID];
#pragma unroll
    for (int k = 0; k < HID; ++k) {
        v2f ai = splat(bih0[k]          + bhh0[k]);
        v2f af = splat(bih0[HID + k]    + bhh0[HID + k]);
        v2f ag = splat(bih0[2*HID + k]  + bhh0[2*HID + k]);
        v2f ao = splat(bih0[3*HID + k]  + bhh0[3*HID + k]);
#pragma unroll
        for (int j = 0; j < IN_DIM; ++j) {
            ai = vfma(splat(Wih0[(k)*IN_DIM + j]),         xv[j], ai);
            af = vfma(splat(Wih0[(HID + k)*IN_DIM + j]),   xv[j], af);
            ag = vfma(splat(Wih0[(2*HID + k)*IN_DIM + j]), xv[j], ag);
            ao = vfma(splat(Wih0[(3*HID + k)*IN_DIM + j]), xv[j], ao);
        }
#pragma unroll
        for (int kk = 0; kk < HID; ++kk) {
            ai = vfma(splat(Whh0[(k)*HID + kk]),         hv[kk], ai);
            af = vfma(splat(Whh0[(HID + k)*HID + kk]),   hv[kk], af);
            ag = vfma(splat(Whh0[(2*HID + k)*HID + kk]), hv[kk], ag);
            ao = vfma(splat(Whh0[(3*HID + k)*HID + kk]), hv[kk], ao);
        }
        v2f ig = sigmoid2(ai);
        v2f fg = sigmoid2(af);
        v2f gg = tanh2(ag);
        v2f og = sigmoid2(ao);
        v2f cn = vfma(fg, cv[k], ig * gg);
        h1[k] = og * tanh2(cn);
    }

    // ---- layer 1 state ----
    const long long off1 = (long long)B * HID;
    const float* h1p = h0 + off1 + e0 * HID;
    const float* c1p = c0 + off1 + e0 * HID;
#pragma unroll
    for (int k = 0; k < HID; ++k) {
        hv[k].x = h1p[k];          hv[k].y = h1p[k + HID * eb];
        cv[k].x = c1p[k];          cv[k].y = c1p[k + HID * eb];
    }

    // ---- layer 1 ----
    v2f h2[HID];
#pragma unroll
    for (int k = 0; k < HID; ++k) {
        v2f ai = splat(bih1[k]          + bhh1[k]);
        v2f af = splat(bih1[HID + k]    + bhh1[HID + k]);
        v2f ag = splat(bih1[2*HID + k]  + bhh1[2*HID + k]);
        v2f ao = splat(bih1[3*HID + k]  + bhh1[3*HID + k]);
#pragma unroll
        for (int j = 0; j < HID; ++j) {
            ai = vfma(splat(Wih1[(k)*HID + j]),         h1[j], ai);
            af = vfma(splat(Wih1[(HID + k)*HID + j]),   h1[j], af);
            ag = vfma(splat(Wih1[(2*HID + k)*HID + j]), h1[j], ag);
            ao = vfma(splat(Wih1[(3*HID + k)*HID + j]), h1[j], ao);
        }
#pragma unroll
        for (int kk = 0; kk < HID; ++kk) {
            ai = vfma(splat(Whh1[(k)*HID + kk]),         hv[kk], ai);
            af = vfma(splat(Whh1[(HID + k)*HID + kk]),   hv[kk], af);
            ag = vfma(splat(Whh1[(2*HID + k)*HID + kk]), hv[kk], ag);
            ao = vfma(splat(Whh1[(3*HID + k)*HID + kk]), hv[kk], ao);
        }
        v2f ig = sigmoid2(ai);
        v2f fg = sigmoid2(af);
        v2f gg = tanh2(ag);
        v2f og = sigmoid2(ao);
        v2f cn = vfma(fg, cv[k], ig * gg);
        h2[k] = og * tanh2(cn);
    }

    // ---- linear head + tanh ----
    v2f o = splat(blin[0]);
#pragma unroll
    for (int k = 0; k < HID; ++k) o = vfma(splat(Wlin[k]), h2[k], o);
    v2f r = tanh2(o);

    if (eb) {
        *(v2f*)(out + e0) = r;   // e0 even -> 8-byte aligned
    } else {
        out[e0] = r.x;
    }
}

extern "C" void kernel_launch(void* const* d_in, const int* in_sizes, int n_in,
                              void* d_out, int out_size, void* d_ws, size_t ws_size,
                              hipStream_t stream) {
    const float* x    = (const float*)d_in[0];
    const float* h0   = (const float*)d_in[1];
    const float* c0   = (const float*)d_in[2];
    const float* Wih0 = (const float*)d_in[3];
    const float* Whh0 = (const float*)d_in[4];
    const float* bih0 = (const float*)d_in[5];
    const float* bhh0 = (const float*)d_in[6];
    const float* Wih1 = (const float*)d_in[7];
    const float* Whh1 = (const float*)d_in[8];
    const float* bih1 = (const float*)d_in[9];
    const float* bhh1 = (const float*)d_in[10];
    const float* Wlin = (const float*)d_in[11];
    const float* blin = (const float*)d_in[12];
    float* out = (float*)d_out;

    const int B = in_sizes[0] / IN_DIM;
    const int elems_per_block = 2 * BLK;
    const int grid = (B + elems_per_block - 1) / elems_per_block;
    lstm2_head_pk<<<grid, BLK, 0, stream>>>(
        x, h0, c0, Wih0, Whh0, bih0, bhh0, Wih1, Whh1, bih1, bhh1,
        Wlin, blin, out, B);
}